// Round 12
// baseline (57.563 us; speedup 1.0000x reference)
//
#include <hip/hip_runtime.h>
#include <math.h>

#define BLOCK 256
#define CN    1024          // refs staged in LDS per chunk
#define NT    (CN / 32)     // 32 col-tiles per chunk

typedef _Float16 f16;
typedef _Float16 f16x8 __attribute__((ext_vector_type(8)));
typedef float f32x16 __attribute__((ext_vector_type(16)));
typedef unsigned long long u64;

union HU { f16 h; unsigned short u; };
static __device__ __forceinline__ unsigned short h16(float x) {
    HU v; v.h = (f16)x; return v.u;
}
static __device__ __forceinline__ u64 shflxor32_u64(u64 v, int m) {
    unsigned lo = (unsigned)v, hi = (unsigned)(v >> 32);
    lo = __shfl_xor(lo, m, 32);
    hi = __shfl_xor(hi, m, 32);
    return ((u64)hi << 32) | lo;
}

// MFMA chamfer scan — EXACTLY the R9-verified structure (absmax 0.0 on HW):
// A = queries (lanes 0-31, elems 0-2), B = refs from LDS (lanes 0-31 real,
// lanes 32-63 read a zero stub), D[row=query][col=ref-in-tile] with
// col=lane&31, row=(reg&3)+8*(reg>>2)+4*(lane>>5).
//   e = d^2 + 64 - ||q||^2 = A . B + w,   w = ||r||^2 + 64 (f32, from lds_w)
// DELTA vs R9 (the only change, numerics identical): instead of splatting w
// into the accumulator C operand per tile (16 register writes/tile of AGPR
// churn — R9's measured 176 inst/tile vs ~73 static), C is a hoisted zero
// vector (D and C are separate operands, so zero per-tile cost) and w is
// added at key time: key = (bits(acc[r]+wval) & ~127) | tj. Same f32
// quantities, same rounding scale. R10/R11's w-in-operand encodings are
// abandoned (both failed for incompletely-explained reasons).
// Key: e>0 so u32 order == float order; tj (7-bit direction-global tile idx)
// in masked low bits; butterfly min across the 32 cols per half-wave; one
// atomicMin(u64) per query row with key64=(kmin<<5)|col, low 12 bits =
// global ref idx. min is commutative/idempotent => deterministic; ties pick
// lowest ref index (jnp.argmin first-occurrence). The reduce kernel
// recomputes the winning distance EXACTLY from raw f32 coords.
__global__ __launch_bounds__(BLOCK, 4)
void chamfer_mfma_kernel(const float* __restrict__ pc_src,
                         const float* __restrict__ pc_dst,
                         u64* __restrict__ part,   // [B*M] dir0 then [B*N] dir1
                         int M, int N, int B, int Zc0) {
    __shared__ uint4 lds_ref[CN + 1];   // f16(-2x,-2y,-2z),pad; [CN]=zero stub
    __shared__ float lds_w[CN];         // ||r||^2 + 64 (f32)

    const int rg = blockIdx.x;          // row-group of 128 queries
    const int b  = blockIdx.y;
    const int z  = blockIdx.z;
    const int dir = (z >= Zc0) ? 1 : 0;
    const int chunk = dir ? (z - Zc0) : z;

    const int NQ = dir ? N : M;
    const int NR = dir ? M : N;
    const float* pcq = dir ? pc_dst : pc_src;
    const float* pcr = dir ? pc_src : pc_dst;
    u64* pp = part + (dir ? (size_t)B * M : (size_t)0) + (size_t)b * NQ;

    const int tid = threadIdx.x;
    const int lane = tid & 63;
    const int wid = tid >> 6;           // wave 0..3
    const int n0 = chunk * CN;

    // ---- stage refs (coalesced f32 loads; convert once per block) ----
    const float* rb = pcr + (size_t)b * 3 * NR + n0;
    for (int i = tid; i < CN; i += BLOCK) {
        const float rx = rb[i], ry = rb[NR + i], rz = rb[2 * NR + i];
        const unsigned u0 = (unsigned)h16(-2.0f * rx) | ((unsigned)h16(-2.0f * ry) << 16);
        const unsigned u1 = (unsigned)h16(-2.0f * rz);
        lds_ref[i] = make_uint4(u0, u1, 0u, 0u);
        lds_w[i] = fmaf(rx, rx, fmaf(ry, ry, rz * rz)) + 64.0f;
    }
    if (tid == 0) lds_ref[CN] = make_uint4(0u, 0u, 0u, 0u);

    // ---- A fragment: this wave's 32 query rows ----
    const int row0 = rg * 128 + wid * 32;
    f16x8 afrag = {0, 0, 0, 0, 0, 0, 0, 0};
    if (lane < 32) {
        const float* qb = pcq + (size_t)b * 3 * NQ + row0 + lane;
        afrag[0] = (f16)qb[0];
        afrag[1] = (f16)qb[NQ];
        afrag[2] = (f16)qb[2 * NQ];
    }

    f32x16 czero;
#pragma unroll
    for (int r = 0; r < 16; ++r) czero[r] = 0.0f;   // hoisted C (never rewritten)

    __syncthreads();

    const int col = lane & 31;
    const bool lo = (lane < 32);
    const uint4* bptr = lo ? &lds_ref[col] : &lds_ref[CN];  // hi lanes: zero stub
    const int bstep = lo ? 32 : 0;

    unsigned kmin[16];
#pragma unroll
    for (int r = 0; r < 16; ++r) kmin[r] = 0xFFFFFFFFu;

    const unsigned emask = ~127u;
    const unsigned tj0 = (unsigned)(chunk * NT);

    for (int t = 0; t < NT; ++t) {
        union { uint4 u; f16x8 h; } rv;
        rv.u = *bptr;                     // ds_read_b128 (B fragment)
        bptr += bstep;
        const float wval = lds_w[t * 32 + col];
        f32x16 acc = __builtin_amdgcn_mfma_f32_32x32x16_f16(afrag, rv.h, czero, 0, 0, 0);
        const unsigned tj = tj0 + (unsigned)t;
#pragma unroll
        for (int r = 0; r < 16; ++r) {
            const unsigned key = (__float_as_uint(acc[r] + wval) & emask) | tj;
            kmin[r] = key < kmin[r] ? key : kmin[r];
        }
    }

    // ---- per-row min across the 32 cols (butterfly within each half) ----
    const int rhalf = (lane >> 5) * 4;
#pragma unroll
    for (int r = 0; r < 16; ++r) {
        u64 k64 = ((u64)kmin[r] << 5) | (unsigned)col;
        for (int m2 = 1; m2 <= 16; m2 <<= 1) {
            const u64 o = shflxor32_u64(k64, m2);
            k64 = (o < k64) ? o : k64;
        }
        if (col == 0) {
            const int row = (r & 3) + 8 * (r >> 2) + rhalf;
            atomicMin(&pp[row0 + row], k64);
        }
    }
}

// Epilogue: one thread per query (both directions concatenated in part).
// Low 12 bits of key64 = global argmin ref index; recompute the winning
// distance EXACTLY from raw f32 coords, weight by sigma, block-reduce,
// one atomicAdd per block.
__global__ void chamfer_reduce_kernel(const float* __restrict__ pc_src,
                                      const float* __restrict__ pc_dst,
                                      const float* __restrict__ sig_src,
                                      const float* __restrict__ sig_dst,
                                      const u64* __restrict__ part,
                                      float* __restrict__ out,
                                      int M, int N, int B) {
    __shared__ float red[BLOCK];
    const int TT = blockIdx.x * BLOCK + threadIdx.x;
    const int dir = (TT >= B * M);           // uniform per block (B*M % 256 == 0)
    const int t = dir ? TT - B * M : TT;     // t = b*NQ + q

    const int NQ = dir ? N : M;
    const int NR = dir ? M : N;
    const float* pcq  = dir ? pc_dst : pc_src;
    const float* pcr  = dir ? pc_src : pc_dst;
    const float* sigq = dir ? sig_dst : sig_src;
    const float* sigr = dir ? sig_src : sig_dst;
    const float scale = 1.0f / (float)(B * NQ);

    const int b = t / NQ;
    const int q = t - b * NQ;

    const int gidx = (int)((unsigned)part[TT] & (unsigned)(NR - 1));

    const float* qbase = pcq + (size_t)b * 3 * NQ;
    const float* rbase = pcr + (size_t)b * 3 * NR;
    const float dx = qbase[q]          - rbase[gidx];
    const float dy = qbase[NQ + q]     - rbase[NR + gidx];
    const float dz = qbase[2 * NQ + q] - rbase[2 * NR + gidx];
    const float dist = sqrtf(fmaf(dx, dx, fmaf(dy, dy, dz * dz)));

    const float s = 0.5f * (sigq[t] + sigr[(size_t)b * NR + gidx]);
    red[threadIdx.x] = dist * s * scale;
    __syncthreads();

    for (int w = BLOCK / 2; w > 0; w >>= 1) {
        if (threadIdx.x < w) red[threadIdx.x] += red[threadIdx.x + w];
        __syncthreads();
    }
    if (threadIdx.x == 0) atomicAdd(out, red[0]);
}

extern "C" void kernel_launch(void* const* d_in, const int* in_sizes, int n_in,
                              void* d_out, int out_size, void* d_ws, size_t ws_size,
                              hipStream_t stream) {
    const float* pc_src  = (const float*)d_in[0];   // [B,3,M]
    const float* pc_dst  = (const float*)d_in[1];   // [B,3,N]
    const float* sig_src = (const float*)d_in[2];   // [B,M]
    const float* sig_dst = (const float*)d_in[3];   // [B,N]
    float* out = (float*)d_out;

    const int B = 8;
    const int M = in_sizes[2] / B;   // 4096
    const int N = in_sizes[3] / B;   // 4096

    u64* part = (u64*)d_ws;          // B*M dir0 keys, then B*N dir1 keys
    const size_t partBytes = (size_t)B * (M + N) * sizeof(u64);   // 512 KiB

    hipMemsetAsync(part, 0xFF, partBytes, stream);   // u64 max sentinels
    hipMemsetAsync(d_out, 0, sizeof(float), stream);

    const int Zc0 = N / CN;          // chunks for dir0 (refs = dst)
    const int Zc1 = M / CN;          // chunks for dir1 (refs = src)

    {   // MFMA min-scan, both directions: grid (32, 8, 8) = 2048 blocks
        dim3 grid(M / 128, B, Zc0 + Zc1);
        chamfer_mfma_kernel<<<grid, BLOCK, 0, stream>>>(
            pc_src, pc_dst, part, M, N, B, Zc0);
    }
    {   // epilogue over all queries of both directions
        dim3 rgrid((B * (M + N)) / BLOCK);
        chamfer_reduce_kernel<<<rgrid, BLOCK, 0, stream>>>(
            pc_src, pc_dst, sig_src, sig_dst, part, out, M, N, B);
    }
}

// Round 13
// 49.741 us; speedup vs baseline: 1.1572x; 1.1572x over previous
//
#include <hip/hip_runtime.h>
#include <math.h>

#define BLOCK 256
#define QPT 8     // queries per thread
#define CS  64    // refs per chunk (local idx 0..63 in masked low key bits)

typedef unsigned long long u64;

// Setup: pack refs into uniform-loadable uint4(-2x,-2y,-2z, ||r||^2+64),
// init part sentinels, zero out. One dispatch replaces both memsets.
// packed: [B*N dir0 refs = dst][B*M dir1 refs = src]; part: [B*M][B*N].
__global__ void chamfer_setup_kernel(const float* __restrict__ pc_src,
                                     const float* __restrict__ pc_dst,
                                     uint4* __restrict__ packed,
                                     u64* __restrict__ part,
                                     float* __restrict__ out,
                                     int M, int N, int B) {
    const int t = blockIdx.x * BLOCK + threadIdx.x;
    const int TOT0 = B * N;
    const int dir = (t >= TOT0);
    const int NR = dir ? M : N;
    const float* pc = dir ? pc_src : pc_dst;
    const int tt = dir ? t - TOT0 : t;
    const int b = tt / NR, i = tt - b * NR;
    const float* rb = pc + (size_t)b * 3 * NR;
    const float rx = rb[i], ry = rb[NR + i], rz = rb[2 * NR + i];
    uint4 v;
    v.x = __float_as_uint(-2.0f * rx);
    v.y = __float_as_uint(-2.0f * ry);
    v.z = __float_as_uint(-2.0f * rz);
    v.w = __float_as_uint(fmaf(rx, rx, fmaf(ry, ry, rz * rz)) + 64.0f);
    packed[t] = v;
    part[t] = ~0ull;                 // same element count B*(M+N)
    if (t == 0) *out = 0.0f;
}

// Min-scan with NO LDS in the hot loop. Ref chunk (wave-uniform address ->
// s_load_dwordx4, SGPR-resident, scalar-pipe prefetch) replaces R1-R12's
// broadcast ds_read + lgkmcnt dependency — the one structural element every
// ~40us-wall variant shared. Per pair: 3 v_fma (1 SGPR coeff each, legal) +
// v_and_or + v_min = ~5.3 slots incl. the per-ref v_mov of w (amortized over
// QPT=8 queries). e = d^2 + 64 - ||q||^2 > 0 so u32 order == float order;
// low 6 bits carry local ref idx (selection perturbed only within ~5e-4 d^2;
// the reduce kernel recomputes the winning distance EXACTLY from raw f32).
// Epilogue: one device-scope atomicMin(u64) per (query, chunk), key =
// (masked_e << 32) | global_idx — commutative/idempotent => deterministic;
// ties pick lowest global index (jnp.argmin first-occurrence).
__global__ __launch_bounds__(BLOCK, 8)
void chamfer_min_kernel(const uint4* __restrict__ packed,
                        const float* __restrict__ pc_src,
                        const float* __restrict__ pc_dst,
                        u64* __restrict__ part,
                        int M, int N, int B, int Zc0) {
    const int b = blockIdx.y;
    const int z = blockIdx.z;
    const int dir = (z >= Zc0) ? 1 : 0;
    const int chunk = dir ? (z - Zc0) : z;

    const int NQ = dir ? N : M;
    const float* pcq = dir ? pc_dst : pc_src;
    const uint4* rp = packed
        + (dir ? (size_t)B * N + (size_t)b * M : (size_t)b * N)
        + (size_t)chunk * CS;
    u64* pp = part + (dir ? (size_t)B * M : (size_t)0) + (size_t)b * NQ;

    const int tid = threadIdx.x;
    const int q0 = blockIdx.x * (BLOCK * QPT) + tid;
    const float* qb = pcq + (size_t)b * 3 * NQ;

    float qx[QPT], qy[QPT], qz[QPT];
    unsigned kmin[QPT];
#pragma unroll
    for (int j = 0; j < QPT; ++j) {
        const int q = q0 + j * BLOCK;
        qx[j] = qb[q];
        qy[j] = qb[NQ + q];
        qz[j] = qb[2 * NQ + q];
        kmin[j] = 0xFFFFFFFFu;
    }

#pragma unroll 8
    for (int i = 0; i < CS; ++i) {
        const uint4 rv = rp[i];          // wave-uniform -> s_load_dwordx4
        const float rx = __uint_as_float(rv.x);
        const float ry = __uint_as_float(rv.y);
        const float rz = __uint_as_float(rv.z);
        const float wv = __uint_as_float(rv.w);
        const unsigned idx = (unsigned)i;
#pragma unroll
        for (int j = 0; j < QPT; ++j) {
            const float e = fmaf(qx[j], rx, fmaf(qy[j], ry, fmaf(qz[j], rz, wv)));
            const unsigned key = (__float_as_uint(e) & ~63u) | idx;
            kmin[j] = key < kmin[j] ? key : kmin[j];
        }
    }

    const unsigned n0 = (unsigned)(chunk * CS);
#pragma unroll
    for (int j = 0; j < QPT; ++j) {
        const int q = q0 + j * BLOCK;
        const u64 key = ((u64)(kmin[j] & ~63u) << 32) | (u64)(n0 + (kmin[j] & 63u));
        atomicMin(&pp[q], key);
    }
}

// Epilogue: one thread per query (both directions concatenated in part).
// Low 32 bits of key64 = global argmin ref index; recompute the winning
// distance EXACTLY from raw f32 coords, weight by sigma, block-reduce,
// one atomicAdd per block.
__global__ void chamfer_reduce_kernel(const float* __restrict__ pc_src,
                                      const float* __restrict__ pc_dst,
                                      const float* __restrict__ sig_src,
                                      const float* __restrict__ sig_dst,
                                      const u64* __restrict__ part,
                                      float* __restrict__ out,
                                      int M, int N, int B) {
    __shared__ float red[BLOCK];
    const int TT = blockIdx.x * BLOCK + threadIdx.x;
    const int dir = (TT >= B * M);           // uniform per block (B*M % 256 == 0)
    const int t = dir ? TT - B * M : TT;     // t = b*NQ + q

    const int NQ = dir ? N : M;
    const int NR = dir ? M : N;
    const float* pcq  = dir ? pc_dst : pc_src;
    const float* pcr  = dir ? pc_src : pc_dst;
    const float* sigq = dir ? sig_dst : sig_src;
    const float* sigr = dir ? sig_src : sig_dst;
    const float scale = 1.0f / (float)(B * NQ);

    const int b = t / NQ;
    const int q = t - b * NQ;

    const int gidx = (int)(unsigned)part[TT];

    const float* qbase = pcq + (size_t)b * 3 * NQ;
    const float* rbase = pcr + (size_t)b * 3 * NR;
    const float dx = qbase[q]          - rbase[gidx];
    const float dy = qbase[NQ + q]     - rbase[NR + gidx];
    const float dz = qbase[2 * NQ + q] - rbase[2 * NR + gidx];
    const float dist = sqrtf(fmaf(dx, dx, fmaf(dy, dy, dz * dz)));

    const float s = 0.5f * (sigq[t] + sigr[(size_t)b * NR + gidx]);
    red[threadIdx.x] = dist * s * scale;
    __syncthreads();

    for (int w = BLOCK / 2; w > 0; w >>= 1) {
        if (threadIdx.x < w) red[threadIdx.x] += red[threadIdx.x + w];
        __syncthreads();
    }
    if (threadIdx.x == 0) atomicAdd(out, red[0]);
}

extern "C" void kernel_launch(void* const* d_in, const int* in_sizes, int n_in,
                              void* d_out, int out_size, void* d_ws, size_t ws_size,
                              hipStream_t stream) {
    const float* pc_src  = (const float*)d_in[0];   // [B,3,M]
    const float* pc_dst  = (const float*)d_in[1];   // [B,3,N]
    const float* sig_src = (const float*)d_in[2];   // [B,M]
    const float* sig_dst = (const float*)d_in[3];   // [B,N]
    float* out = (float*)d_out;

    const int B = 8;
    const int M = in_sizes[2] / B;   // 4096
    const int N = in_sizes[3] / B;   // 4096

    // d_ws layout: part (B*(M+N) u64 = 512 KiB) | packed (B*(M+N) uint4 = 1 MiB)
    u64* part = (u64*)d_ws;
    uint4* packed = (uint4*)((char*)d_ws + (size_t)B * (M + N) * sizeof(u64));

    const int TOT = B * (M + N);     // 65536

    {   // setup: pack refs + sentinels + zero out (replaces both memsets)
        chamfer_setup_kernel<<<TOT / BLOCK, BLOCK, 0, stream>>>(
            pc_src, pc_dst, packed, part, out, M, N, B);
    }
    {   // min-scan, both directions: grid (2, 8, 128) = 2048 blocks, no LDS
        const int Zc0 = N / CS;
        const int Zc1 = M / CS;
        dim3 grid(M / (BLOCK * QPT), B, Zc0 + Zc1);
        chamfer_min_kernel<<<grid, BLOCK, 0, stream>>>(
            packed, pc_src, pc_dst, part, M, N, B, Zc0);
    }
    {   // epilogue over all queries of both directions
        dim3 rgrid(TOT / BLOCK);
        chamfer_reduce_kernel<<<rgrid, BLOCK, 0, stream>>>(
            pc_src, pc_dst, sig_src, sig_dst, part, out, M, N, B);
    }
}